// Round 3
// baseline (286.749 us; speedup 1.0000x reference)
//
#include <hip/hip_runtime.h>
#include <hip/hip_bf16.h>

// out[t,n] = sum_k x[k,t] * W[k,n] + b[n]
// x: [256, 131072] f32 (K-major), W: [256, 256] f32, b: [256] f32
// out: [131072, 256] f32
//
// Split-bf16 MFMA (hi*hi + hi*lo + lo*hi).
// Round-3: BM=32 (32 KB LDS) -> 4 blocks/CU occupancy; full-K single staging
// (1 barrier); epilogue LDS-transpose for fully-coalesced dwordx4 row stores.

#define TOKENS 131072
#define KDIM   256
#define NDIM   256
#define BM     32            // tokens per block
#define NKS    (KDIM / 32)   // 8 MFMA k-steps

typedef __bf16 bf16x8 __attribute__((ext_vector_type(8)));
typedef float  f32x4  __attribute__((ext_vector_type(4)));
typedef unsigned short ushort8 __attribute__((ext_vector_type(8)));

__device__ __forceinline__ unsigned short f32_to_bf16_rne(float f) {
    unsigned int u = __builtin_bit_cast(unsigned int, f);
    u += 0x7fffu + ((u >> 16) & 1u);   // round-to-nearest-even (finite inputs)
    return (unsigned short)(u >> 16);
}
__device__ __forceinline__ float bf16_to_f32(unsigned short h) {
    unsigned int u = ((unsigned int)h) << 16;
    return __builtin_bit_cast(float, u);
}

// ---------------------------------------------------------------------------
// Prep: pack W into B-fragment order, split into hi/lo bf16.
// wp (ushort): hi [0,65536), lo [65536,131072)
// element ((ks*16 + ntg)*64 + lane)*8 + p = W[ks*32 + (lane>>4)*8 + p][ntg*16 + (lane&15)]
// ---------------------------------------------------------------------------
__global__ void prep_w_kernel(const float* __restrict__ W, unsigned short* __restrict__ wp) {
    int tid = blockIdx.x * 256 + threadIdx.x;   // 0..65535
    int p  = tid & 7;
    int l  = (tid >> 3) & 63;
    int nt = (tid >> 9) & 15;
    int ks = tid >> 13;
    int g = l >> 4, c = l & 15;
    int k = ks * 32 + g * 8 + p;
    int n = nt * 16 + c;
    float w = W[k * NDIM + n];
    unsigned short hi = f32_to_bf16_rne(w);
    unsigned short lo = f32_to_bf16_rne(w - bf16_to_f32(hi));
    wp[tid]         = hi;
    wp[65536 + tid] = lo;
}

// ---------------------------------------------------------------------------
// Main GEMM. Block: 256 threads (4 waves). Tile: 32 tokens x full N=256.
// Stage ALL of K once (one barrier), then 8 barrier-free MFMA k-steps.
// LDS fragment slots: slot(ks,g,ms,r) = ks*128 + g*32 + ms*16 + r (16 B each)
//   holds x_bf16[k = ks*32 + g*8 + p][t = ms*16 + r], p = 0..7
// Epilogue: reuse the same 32 KB LDS as f32[32][256] (XOR-swizzled) to emit
// fully-coalesced 1 KB row stores.
// ---------------------------------------------------------------------------
__global__ __launch_bounds__(256, 4)
void xtw_gemm_kernel(const float* __restrict__ x,
                     const unsigned short* __restrict__ wp,
                     const float* __restrict__ bvec,
                     float* __restrict__ out) {
    __shared__ __align__(16) unsigned char smem[32768];   // 32 KiB, dual-use
    unsigned short* lds_hi = (unsigned short*)smem;             // 8192 elems
    unsigned short* lds_lo = (unsigned short*)(smem + 16384);   // 8192 elems

    const int tid  = threadIdx.x;
    const int lane = tid & 63;
    const int wave = tid >> 6;
    const int t0   = blockIdx.x * BM;

    // ---- staging: thread = (token tok, k-block kb); 32 f32 burst ----
    const int tok = tid & 31;
    const int kb  = tid >> 5;          // 0..7 == ks

    float xr[32];
#pragma unroll
    for (int j = 0; j < 32; ++j)
        xr[j] = x[(size_t)(kb * 32 + j) * TOKENS + (t0 + tok)];

    const int ms_w = tok >> 4, r_w = tok & 15;
#pragma unroll
    for (int s = 0; s < 4; ++s) {      // g = s, k = kb*32 + s*8 + p
        ushort8 hv, lv;
#pragma unroll
        for (int p = 0; p < 8; ++p) {
            float f = xr[s * 8 + p];
            unsigned short h = f32_to_bf16_rne(f);
            hv[p] = h;
            lv[p] = f32_to_bf16_rne(f - bf16_to_f32(h));
        }
        const int slot = kb * 128 + s * 32 + ms_w * 16 + r_w;
        *reinterpret_cast<ushort8*>(lds_hi + slot * 8) = hv;
        *reinterpret_cast<ushort8*>(lds_lo + slot * 8) = lv;
    }
    __syncthreads();

    // ---- compute: wave owns n-quadrant [wave*64, wave*64+64) ----
    const int g = lane >> 4, r = lane & 15;

    f32x4 acc[2][4];
#pragma unroll
    for (int ms = 0; ms < 2; ++ms)
#pragma unroll
        for (int nt = 0; nt < 4; ++nt)
            acc[ms][nt] = (f32x4){0.f, 0.f, 0.f, 0.f};

#pragma unroll
    for (int ks = 0; ks < NKS; ++ks) {
        // B fragments for this k-step (L1/L2-resident; vmem queue empty here)
        bf16x8 bhi[4], blo[4];
#pragma unroll
        for (int nt = 0; nt < 4; ++nt) {
            const int ntg = wave * 4 + nt;
            const size_t off = ((size_t)(ks * 16 + ntg) * 64 + lane) * 8;
            bhi[nt] = *reinterpret_cast<const bf16x8*>(wp + off);
            blo[nt] = *reinterpret_cast<const bf16x8*>(wp + 65536 + off);
        }
#pragma unroll
        for (int ms = 0; ms < 2; ++ms) {
            const int slot = ks * 128 + g * 32 + ms * 16 + r;
            bf16x8 ahi = *reinterpret_cast<const bf16x8*>(lds_hi + slot * 8);
            bf16x8 alo = *reinterpret_cast<const bf16x8*>(lds_lo + slot * 8);
#pragma unroll
            for (int nt = 0; nt < 4; ++nt) {
                acc[ms][nt] = __builtin_amdgcn_mfma_f32_16x16x32_bf16(ahi, bhi[nt], acc[ms][nt], 0, 0, 0);
                acc[ms][nt] = __builtin_amdgcn_mfma_f32_16x16x32_bf16(ahi, blo[nt], acc[ms][nt], 0, 0, 0);
                acc[ms][nt] = __builtin_amdgcn_mfma_f32_16x16x32_bf16(alo, bhi[nt], acc[ms][nt], 0, 0, 0);
            }
        }
    }

    // ---- epilogue: bias, LDS transpose (XOR-swizzled), coalesced stores ----
    float bv[4];
#pragma unroll
    for (int nt = 0; nt < 4; ++nt)
        bv[nt] = bvec[wave * 64 + nt * 16 + r];

    __syncthreads();                       // staging LDS fully consumed
    float* fb = (float*)smem;              // f32[32][256], swizzled

#pragma unroll
    for (int ms = 0; ms < 2; ++ms) {
#pragma unroll
        for (int nt = 0; nt < 4; ++nt) {
            const int n = wave * 64 + nt * 16 + r;
#pragma unroll
            for (int jj = 0; jj < 4; ++jj) {
                const int t = ms * 16 + g * 4 + jj;
                const int nswz = n ^ (((t >> 2) & 3) << 4);
                fb[t * 256 + nswz] = acc[ms][nt][jj] + bv[nt];
            }
        }
    }
    __syncthreads();

    // each wave emits full 1 KB rows: 8 rows/wave, 1 dwordx4 per lane per row
#pragma unroll
    for (int rr = 0; rr < 8; ++rr) {
        const int t = rr * 4 + wave;
        const int nswz = (lane * 4) ^ (((t >> 2) & 3) << 4);
        f32x4 v = *reinterpret_cast<const f32x4*>(&fb[t * 256 + nswz]);
        *reinterpret_cast<f32x4*>(&out[(size_t)(t0 + t) * NDIM + lane * 4]) = v;
    }
}

// ---------------------------------------------------------------------------
// Fallback (only if d_ws is unexpectedly tiny): plain f32, correct but slow.
// ---------------------------------------------------------------------------
__global__ void naive_xtw_kernel(const float* __restrict__ x,
                                 const float* __restrict__ W,
                                 const float* __restrict__ b,
                                 float* __restrict__ out) {
    int t = blockIdx.x;
    int n = threadIdx.x;
    float s = b[n];
    for (int k = 0; k < KDIM; ++k)
        s += x[(size_t)k * TOKENS + t] * W[k * NDIM + n];
    out[(size_t)t * NDIM + n] = s;
}

extern "C" void kernel_launch(void* const* d_in, const int* in_sizes, int n_in,
                              void* d_out, int out_size, void* d_ws, size_t ws_size,
                              hipStream_t stream) {
    const float* x = (const float*)d_in[0];
    const float* W = (const float*)d_in[1];
    const float* b = (const float*)d_in[2];
    float* out = (float*)d_out;

    if (ws_size >= (size_t)131072 * sizeof(unsigned short)) {
        unsigned short* wp = (unsigned short*)d_ws;
        prep_w_kernel<<<256, 256, 0, stream>>>(W, wp);
        xtw_gemm_kernel<<<TOKENS / BM, 256, 0, stream>>>(x, wp, b, out);
    } else {
        naive_xtw_kernel<<<TOKENS, 256, 0, stream>>>(x, W, b, out);
    }
}